// Round 1
// baseline (218.663 us; speedup 1.0000x reference)
//
#include <hip/hip_runtime.h>
#include <cstdint>
#include <cstddef>

#define NB 8
#define NS 4096
#define NN 2048
#define NH 768
#define NK 50
#define TS 128
#define HB 32
#define NTILES (NS / TS)   // 32
#define HBLKS (NH / HB)    // 24

// ---------------------------------------------------------------------------
// K1: exact sequential f32 prefix sums along S per (b,h) column (np.cumsum
// semantics). One block = one (b, 32-h slice). 4 waves cooperatively stage
// 128x32 tiles into LDS (double-buffered); lanes 0-31 of wave 0 run the
// sequential accumulation chain and store P rows.
// ---------------------------------------------------------------------------
__global__ __launch_bounds__(256) void k1_prefix(const float* __restrict__ x,
                                                 float* __restrict__ P) {
  const int b    = blockIdx.x / HBLKS;
  const int h0   = (blockIdx.x % HBLKS) * HB;
  const int tid  = threadIdx.x;
  const int lane = tid & 63;
  const int wave = tid >> 6;

  __shared__ float lds[2][TS * HB];

  const float* gx = x + ((size_t)b * NS) * NH + h0;
  float*       gp = P + ((size_t)b * (NS + 1)) * NH + h0;

  float4 r[4];

  auto load_tile = [&](int t) {
#pragma unroll
    for (int j = 0; j < 4; ++j) {
      int elem = (tid + 256 * j) * 4;   // 0..4095
      int row  = elem >> 5;             // /32
      int col  = elem & 31;
      r[j] = *reinterpret_cast<const float4*>(gx + (size_t)(t * TS + row) * NH + col);
    }
  };
  auto write_tile = [&](int slot) {
#pragma unroll
    for (int j = 0; j < 4; ++j) {
      int elem = (tid + 256 * j) * 4;
      *reinterpret_cast<float4*>(&lds[slot][elem]) = r[j];
    }
  };

  load_tile(0);
  write_tile(0);
  if (wave == 0 && lane < HB) gp[lane] = 0.0f;   // P[b,0,h] = 0
  __syncthreads();

  float acc = 0.0f;
  for (int t = 0; t < NTILES; ++t) {
    if (t + 1 < NTILES) load_tile(t + 1);        // issue next-tile loads early
    if (wave == 0 && lane < HB) {
      const float* ld = &lds[t & 1][0];
      float* outp = gp + (size_t)(t * TS + 1) * NH + lane;
#pragma unroll 8
      for (int i = 0; i < TS; ++i) {
        acc += ld[i * HB + lane];                // strict s-order: exact cumsum
        outp[(size_t)i * NH] = acc;
      }
    }
    if (t + 1 < NTILES) write_tile((t + 1) & 1); // other slot: no hazard
    __syncthreads();
  }
}

// ---------------------------------------------------------------------------
// K2: span scores. One wave per span: gather P[start], P[end] rows, per-comp
// (f32) subtract + divide by n_tok (bit-identical to ref's embs), dot with
// the 3 anchors, shuffle-reduce, max.
// ---------------------------------------------------------------------------
__global__ __launch_bounds__(256) void k2_scores(const float* __restrict__ P,
                                                 const int* __restrict__ starts,
                                                 const int* __restrict__ lens,
                                                 const float* __restrict__ anchor,
                                                 float* __restrict__ scores) {
  const int lane  = threadIdx.x & 63;
  const int gwave = blockIdx.x * 4 + (threadIdx.x >> 6);
  const int nwv   = gridDim.x * 4;

  float4 a[3][3];
#pragma unroll
  for (int c = 0; c < 3; ++c)
#pragma unroll
    for (int p = 0; p < 3; ++p)
      a[c][p] = *reinterpret_cast<const float4*>(anchor + c * NH + lane * 4 + p * 256);

  for (int sp = gwave; sp < NB * NN; sp += nwv) {
    const int b  = sp >> 11;                     // / NN
    const int st = starts[sp];
    const int nt = lens[sp] + 1;
    const int en = st + nt;
    const float fnt = (float)nt;
    const float* ps = P + ((size_t)b * (NS + 1) + st) * NH + lane * 4;
    const float* pe = P + ((size_t)b * (NS + 1) + en) * NH + lane * 4;
    float d0 = 0.f, d1 = 0.f, d2 = 0.f;
#pragma unroll
    for (int p = 0; p < 3; ++p) {
      float4 vs = *reinterpret_cast<const float4*>(ps + p * 256);
      float4 ve = *reinterpret_cast<const float4*>(pe + p * 256);
      float ex = (ve.x - vs.x) / fnt;
      float ey = (ve.y - vs.y) / fnt;
      float ez = (ve.z - vs.z) / fnt;
      float ew = (ve.w - vs.w) / fnt;
      d0 += ex * a[0][p].x + ey * a[0][p].y + ez * a[0][p].z + ew * a[0][p].w;
      d1 += ex * a[1][p].x + ey * a[1][p].y + ez * a[1][p].z + ew * a[1][p].w;
      d2 += ex * a[2][p].x + ey * a[2][p].y + ez * a[2][p].z + ew * a[2][p].w;
    }
#pragma unroll
    for (int o = 32; o > 0; o >>= 1) {
      d0 += __shfl_xor(d0, o);
      d1 += __shfl_xor(d1, o);
      d2 += __shfl_xor(d2, o);
    }
    if (lane == 0) scores[sp] = fmaxf(d0, fmaxf(d1, d2));
  }
}

// ---------------------------------------------------------------------------
// K3: top-50 per batch. Keys pack (orderable-f32 score, 2047-n) so max-key
// = (highest score, ties -> smallest index), matching lax.top_k.
// ---------------------------------------------------------------------------
__global__ __launch_bounds__(256) void k3_topk(const float* __restrict__ scores,
                                               int* __restrict__ topidx) {
  const int b   = blockIdx.x;
  const int tid = threadIdx.x;
  __shared__ unsigned long long key[NN];
  __shared__ unsigned long long red[256];
  for (int i = tid; i < NN; i += 256) {
    unsigned u   = __float_as_uint(scores[b * NN + i]);
    unsigned ord = (u & 0x80000000u) ? ~u : (u | 0x80000000u);
    key[i] = ((unsigned long long)ord << 32) | (unsigned)(NN - 1 - i);
  }
  __syncthreads();
  for (int k = 0; k < NK; ++k) {
    unsigned long long m = 0;
    for (int i = tid; i < NN; i += 256) m = (key[i] > m) ? key[i] : m;
    red[tid] = m;
    __syncthreads();
    for (int s2 = 128; s2 > 0; s2 >>= 1) {
      if (tid < s2) { if (red[tid + s2] > red[tid]) red[tid] = red[tid + s2]; }
      __syncthreads();
    }
    if (tid == 0) {
      int n = (NN - 1) - (int)(red[0] & 0xFFFFFFFFull);
      topidx[b * NK + k] = n;
      key[n] = 0;              // remove winner
    }
    __syncthreads();
  }
}

// ---------------------------------------------------------------------------
// K4a: for each selected span (400 total): recompute emb from P-diff, dot
// with the 48 weight rows -> proj[b][k][48] = {rh[4], rt[4], nh[20], nt[20]}.
// ---------------------------------------------------------------------------
__global__ __launch_bounds__(256) void k4a_proj(const float* __restrict__ P,
                                                const int* __restrict__ starts,
                                                const int* __restrict__ lens,
                                                const int* __restrict__ topidx,
                                                const float* __restrict__ rel,
                                                const float* __restrict__ nota,
                                                float* __restrict__ proj) {
  const int gw   = blockIdx.x * 4 + (threadIdx.x >> 6);   // 0..399
  const int lane = threadIdx.x & 63;
  const int b = gw / NK, k = gw % NK;
  const int n  = topidx[b * NK + k];
  const int st = starts[b * NN + n];
  const int nt = lens[b * NN + n] + 1;
  const int en = st + nt;
  const float fnt = (float)nt;
  const float* ps = P + ((size_t)b * (NS + 1) + st) * NH + lane * 4;
  const float* pe = P + ((size_t)b * (NS + 1) + en) * NH + lane * 4;
  float4 e[3];
#pragma unroll
  for (int p = 0; p < 3; ++p) {
    float4 vs = *reinterpret_cast<const float4*>(ps + p * 256);
    float4 ve = *reinterpret_cast<const float4*>(pe + p * 256);
    e[p].x = (ve.x - vs.x) / fnt;
    e[p].y = (ve.y - vs.y) / fnt;
    e[p].z = (ve.z - vs.z) / fnt;
    e[p].w = (ve.w - vs.w) / fnt;
  }
  for (int w = 0; w < 48; ++w) {
    const float* wr;
    if (w < 4)       wr = rel  + (size_t)w * (2 * NH);
    else if (w < 8)  wr = rel  + (size_t)(w - 4) * (2 * NH) + NH;
    else if (w < 28) wr = nota + (size_t)(w - 8) * (2 * NH);
    else             wr = nota + (size_t)(w - 28) * (2 * NH) + NH;
    wr += lane * 4;
    float d = 0.f;
#pragma unroll
    for (int p = 0; p < 3; ++p) {
      float4 wv = *reinterpret_cast<const float4*>(wr + p * 256);
      d += e[p].x * wv.x + e[p].y * wv.y + e[p].z * wv.z + e[p].w * wv.w;
    }
#pragma unroll
    for (int o = 32; o > 0; o >>= 1) d += __shfl_xor(d, o);
    if (lane == 0) proj[((size_t)b * NK + k) * 48 + w] = d;
  }
}

// ---------------------------------------------------------------------------
// K4b: out[b,k1,k2,0] = max_m(nh[k1,m]+nt[k2,m]); out[b,k1,k2,1+r] = rh+rt.
// ---------------------------------------------------------------------------
__global__ __launch_bounds__(256) void k4b_out(const float* __restrict__ proj,
                                               float* __restrict__ out) {
  int idx = blockIdx.x * 256 + threadIdx.x;
  if (idx >= NB * NK * NK) return;
  int b  = idx / (NK * NK);
  int rr = idx % (NK * NK);
  int k1 = rr / NK, k2 = rr % NK;
  const float* p1 = proj + ((size_t)b * NK + k1) * 48;
  const float* p2 = proj + ((size_t)b * NK + k2) * 48;
  float mx = p1[8] + p2[28];
#pragma unroll
  for (int m = 1; m < 20; ++m) mx = fmaxf(mx, p1[8 + m] + p2[28 + m]);
  float* o = out + (size_t)idx * 5;
  o[0] = mx;
#pragma unroll
  for (int r = 0; r < 4; ++r) o[1 + r] = p1[r] + p2[4 + r];
}

// ---------------------------------------------------------------------------
extern "C" void kernel_launch(void* const* d_in, const int* in_sizes, int n_in,
                              void* d_out, int out_size, void* d_ws, size_t ws_size,
                              hipStream_t stream) {
  const float* x      = (const float*)d_in[0];
  const int*   starts = (const int*)d_in[1];
  const int*   lens   = (const int*)d_in[2];
  const float* anchor = (const float*)d_in[3];
  const float* rel    = (const float*)d_in[4];
  const float* nota   = (const float*)d_in[5];
  float* out = (float*)d_out;

  char*  ws     = (char*)d_ws;
  size_t pbytes = (size_t)NB * (NS + 1) * NH * sizeof(float);  // ~100.7 MB
  float* P      = (float*)ws;
  float* scores = (float*)(ws + pbytes);
  int*   topidx = (int*)(ws + pbytes + (size_t)NB * NN * sizeof(float));
  float* proj   = (float*)(ws + pbytes + (size_t)NB * NN * sizeof(float) + 4096);

  hipLaunchKernelGGL(k1_prefix, dim3(NB * HBLKS), dim3(256), 0, stream, x, P);
  hipLaunchKernelGGL(k2_scores, dim3(1024), dim3(256), 0, stream,
                     P, starts, lens, anchor, scores);
  hipLaunchKernelGGL(k3_topk, dim3(NB), dim3(256), 0, stream, scores, topidx);
  hipLaunchKernelGGL(k4a_proj, dim3(NB * NK / 4), dim3(256), 0, stream,
                     P, starts, lens, topidx, rel, nota, proj);
  hipLaunchKernelGGL(k4b_out, dim3((NB * NK * NK + 255) / 256), dim3(256), 0, stream,
                     proj, out);
}

// Round 2
// 179.028 us; speedup vs baseline: 1.2214x; 1.2214x over previous
//
#include <hip/hip_runtime.h>
#include <cstdint>
#include <cstddef>

#define NB 8
#define NS 4096
#define NN 2048
#define NH 768
#define NK 50

// ---------------------------------------------------------------------------
// K1: exact sequential f32 prefix sums along S per (b,h) column (np.cumsum
// semantics). One wave (64 lanes) owns a 64-wide h-slice of one batch; lane
// <-> h column. Register-resident 2-deep x 64-row pipeline: loads for chunk
// c+1 issue before the dependent-add/store pass over chunk c, keeping ~60
// coalesced 256B loads in flight per wave. No LDS, no barriers.
// Arithmetic (strict s-order f32 adds) is bit-identical to np.cumsum.
// ---------------------------------------------------------------------------
#define K1U 64                      // rows per chunk
#define K1CH (NS / K1U)             // 64 chunks

__global__ __launch_bounds__(64) void k1_prefix(const float* __restrict__ x,
                                                float* __restrict__ P) {
  const int w = blockIdx.x;                 // 0..95 = 8 b x 12 h-slices
  const int b = w / 12;
  const int h = (w % 12) * 64 + threadIdx.x;

  const float* gx = x + (size_t)b * NS * NH + h;
  float*       gp = P + (size_t)b * (NS + 1) * NH + h;

  gp[0] = 0.0f;                             // P[b,0,h] = 0

  float va[K1U], vb[K1U];
#pragma unroll
  for (int j = 0; j < K1U; ++j) va[j] = gx[(size_t)j * NH];

  float acc = 0.0f;
  for (int c = 0; c < K1CH; c += 2) {
    // issue loads for chunk c+1 (always exists: K1CH even, c <= K1CH-2)
    {
      const float* src = gx + (size_t)(c + 1) * K1U * NH;
#pragma unroll
      for (int j = 0; j < K1U; ++j) vb[j] = src[(size_t)j * NH];
    }
    // sequential accumulate + store chunk c
    {
      float* op = gp + ((size_t)c * K1U + 1) * NH;
#pragma unroll
      for (int j = 0; j < K1U; ++j) { acc += va[j]; op[(size_t)j * NH] = acc; }
    }
    // issue loads for chunk c+2
    if (c + 2 < K1CH) {
      const float* src = gx + (size_t)(c + 2) * K1U * NH;
#pragma unroll
      for (int j = 0; j < K1U; ++j) va[j] = src[(size_t)j * NH];
    }
    // sequential accumulate + store chunk c+1
    {
      float* op = gp + (((size_t)(c + 1) * K1U) + 1) * NH;
#pragma unroll
      for (int j = 0; j < K1U; ++j) { acc += vb[j]; op[(size_t)j * NH] = acc; }
    }
  }
}

// ---------------------------------------------------------------------------
// K2: span scores. One wave per span: gather P[start], P[end] rows, per-comp
// (f32) subtract + divide by n_tok (bit-identical to ref's embs), dot with
// the 3 anchors, shuffle-reduce, max.  [UNCHANGED from passing R1 version]
// ---------------------------------------------------------------------------
__global__ __launch_bounds__(256) void k2_scores(const float* __restrict__ P,
                                                 const int* __restrict__ starts,
                                                 const int* __restrict__ lens,
                                                 const float* __restrict__ anchor,
                                                 float* __restrict__ scores) {
  const int lane  = threadIdx.x & 63;
  const int gwave = blockIdx.x * 4 + (threadIdx.x >> 6);
  const int nwv   = gridDim.x * 4;

  float4 a[3][3];
#pragma unroll
  for (int c = 0; c < 3; ++c)
#pragma unroll
    for (int p = 0; p < 3; ++p)
      a[c][p] = *reinterpret_cast<const float4*>(anchor + c * NH + lane * 4 + p * 256);

  for (int sp = gwave; sp < NB * NN; sp += nwv) {
    const int b  = sp >> 11;                     // / NN
    const int st = starts[sp];
    const int nt = lens[sp] + 1;
    const int en = st + nt;
    const float fnt = (float)nt;
    const float* ps = P + ((size_t)b * (NS + 1) + st) * NH + lane * 4;
    const float* pe = P + ((size_t)b * (NS + 1) + en) * NH + lane * 4;
    float d0 = 0.f, d1 = 0.f, d2 = 0.f;
#pragma unroll
    for (int p = 0; p < 3; ++p) {
      float4 vs = *reinterpret_cast<const float4*>(ps + p * 256);
      float4 ve = *reinterpret_cast<const float4*>(pe + p * 256);
      float ex = (ve.x - vs.x) / fnt;
      float ey = (ve.y - vs.y) / fnt;
      float ez = (ve.z - vs.z) / fnt;
      float ew = (ve.w - vs.w) / fnt;
      d0 += ex * a[0][p].x + ey * a[0][p].y + ez * a[0][p].z + ew * a[0][p].w;
      d1 += ex * a[1][p].x + ey * a[1][p].y + ez * a[1][p].z + ew * a[1][p].w;
      d2 += ex * a[2][p].x + ey * a[2][p].y + ez * a[2][p].z + ew * a[2][p].w;
    }
#pragma unroll
    for (int o = 32; o > 0; o >>= 1) {
      d0 += __shfl_xor(d0, o);
      d1 += __shfl_xor(d1, o);
      d2 += __shfl_xor(d2, o);
    }
    if (lane == 0) scores[sp] = fmaxf(d0, fmaxf(d1, d2));
  }
}

// ---------------------------------------------------------------------------
// K3: top-50 per batch. Keys pack (orderable-f32 score, 2047-n) so max-key
// = (highest score, ties -> smallest index), matching lax.top_k. [UNCHANGED]
// ---------------------------------------------------------------------------
__global__ __launch_bounds__(256) void k3_topk(const float* __restrict__ scores,
                                               int* __restrict__ topidx) {
  const int b   = blockIdx.x;
  const int tid = threadIdx.x;
  __shared__ unsigned long long key[NN];
  __shared__ unsigned long long red[256];
  for (int i = tid; i < NN; i += 256) {
    unsigned u   = __float_as_uint(scores[b * NN + i]);
    unsigned ord = (u & 0x80000000u) ? ~u : (u | 0x80000000u);
    key[i] = ((unsigned long long)ord << 32) | (unsigned)(NN - 1 - i);
  }
  __syncthreads();
  for (int k = 0; k < NK; ++k) {
    unsigned long long m = 0;
    for (int i = tid; i < NN; i += 256) m = (key[i] > m) ? key[i] : m;
    red[tid] = m;
    __syncthreads();
    for (int s2 = 128; s2 > 0; s2 >>= 1) {
      if (tid < s2) { if (red[tid + s2] > red[tid]) red[tid] = red[tid + s2]; }
      __syncthreads();
    }
    if (tid == 0) {
      int n = (NN - 1) - (int)(red[0] & 0xFFFFFFFFull);
      topidx[b * NK + k] = n;
      key[n] = 0;              // remove winner
    }
    __syncthreads();
  }
}

// ---------------------------------------------------------------------------
// K4a: for each selected span (400 total): recompute emb from P-diff, dot
// with the 48 weight rows -> proj[b][k][48]. [UNCHANGED]
// ---------------------------------------------------------------------------
__global__ __launch_bounds__(256) void k4a_proj(const float* __restrict__ P,
                                                const int* __restrict__ starts,
                                                const int* __restrict__ lens,
                                                const int* __restrict__ topidx,
                                                const float* __restrict__ rel,
                                                const float* __restrict__ nota,
                                                float* __restrict__ proj) {
  const int gw   = blockIdx.x * 4 + (threadIdx.x >> 6);   // 0..399
  const int lane = threadIdx.x & 63;
  const int b = gw / NK, k = gw % NK;
  const int n  = topidx[b * NK + k];
  const int st = starts[b * NN + n];
  const int nt = lens[b * NN + n] + 1;
  const int en = st + nt;
  const float fnt = (float)nt;
  const float* ps = P + ((size_t)b * (NS + 1) + st) * NH + lane * 4;
  const float* pe = P + ((size_t)b * (NS + 1) + en) * NH + lane * 4;
  float4 e[3];
#pragma unroll
  for (int p = 0; p < 3; ++p) {
    float4 vs = *reinterpret_cast<const float4*>(ps + p * 256);
    float4 ve = *reinterpret_cast<const float4*>(pe + p * 256);
    e[p].x = (ve.x - vs.x) / fnt;
    e[p].y = (ve.y - vs.y) / fnt;
    e[p].z = (ve.z - vs.z) / fnt;
    e[p].w = (ve.w - vs.w) / fnt;
  }
  for (int w = 0; w < 48; ++w) {
    const float* wr;
    if (w < 4)       wr = rel  + (size_t)w * (2 * NH);
    else if (w < 8)  wr = rel  + (size_t)(w - 4) * (2 * NH) + NH;
    else if (w < 28) wr = nota + (size_t)(w - 8) * (2 * NH);
    else             wr = nota + (size_t)(w - 28) * (2 * NH) + NH;
    wr += lane * 4;
    float d = 0.f;
#pragma unroll
    for (int p = 0; p < 3; ++p) {
      float4 wv = *reinterpret_cast<const float4*>(wr + p * 256);
      d += e[p].x * wv.x + e[p].y * wv.y + e[p].z * wv.z + e[p].w * wv.w;
    }
#pragma unroll
    for (int o = 32; o > 0; o >>= 1) d += __shfl_xor(d, o);
    if (lane == 0) proj[((size_t)b * NK + k) * 48 + w] = d;
  }
}

// ---------------------------------------------------------------------------
// K4b: out[b,k1,k2,0] = max_m(nh[k1,m]+nt[k2,m]); out[b,k1,k2,1+r] = rh+rt.
// [UNCHANGED]
// ---------------------------------------------------------------------------
__global__ __launch_bounds__(256) void k4b_out(const float* __restrict__ proj,
                                               float* __restrict__ out) {
  int idx = blockIdx.x * 256 + threadIdx.x;
  if (idx >= NB * NK * NK) return;
  int b  = idx / (NK * NK);
  int rr = idx % (NK * NK);
  int k1 = rr / NK, k2 = rr % NK;
  const float* p1 = proj + ((size_t)b * NK + k1) * 48;
  const float* p2 = proj + ((size_t)b * NK + k2) * 48;
  float mx = p1[8] + p2[28];
#pragma unroll
  for (int m = 1; m < 20; ++m) mx = fmaxf(mx, p1[8 + m] + p2[28 + m]);
  float* o = out + (size_t)idx * 5;
  o[0] = mx;
#pragma unroll
  for (int r = 0; r < 4; ++r) o[1 + r] = p1[r] + p2[4 + r];
}

// ---------------------------------------------------------------------------
extern "C" void kernel_launch(void* const* d_in, const int* in_sizes, int n_in,
                              void* d_out, int out_size, void* d_ws, size_t ws_size,
                              hipStream_t stream) {
  const float* x      = (const float*)d_in[0];
  const int*   starts = (const int*)d_in[1];
  const int*   lens   = (const int*)d_in[2];
  const float* anchor = (const float*)d_in[3];
  const float* rel    = (const float*)d_in[4];
  const float* nota   = (const float*)d_in[5];
  float* out = (float*)d_out;

  char*  ws     = (char*)d_ws;
  size_t pbytes = (size_t)NB * (NS + 1) * NH * sizeof(float);  // ~100.7 MB
  float* P      = (float*)ws;
  float* scores = (float*)(ws + pbytes);
  int*   topidx = (int*)(ws + pbytes + (size_t)NB * NN * sizeof(float));
  float* proj   = (float*)(ws + pbytes + (size_t)NB * NN * sizeof(float) + 4096);

  hipLaunchKernelGGL(k1_prefix, dim3(NB * (NH / 64)), dim3(64), 0, stream, x, P);
  hipLaunchKernelGGL(k2_scores, dim3(1024), dim3(256), 0, stream,
                     P, starts, lens, anchor, scores);
  hipLaunchKernelGGL(k3_topk, dim3(NB), dim3(256), 0, stream, scores, topidx);
  hipLaunchKernelGGL(k4a_proj, dim3(NB * NK / 4), dim3(256), 0, stream,
                     P, starts, lens, topidx, rel, nota, proj);
  hipLaunchKernelGGL(k4b_out, dim3((NB * NK * NK + 255) / 256), dim3(256), 0, stream,
                     proj, out);
}

// Round 3
// 177.263 us; speedup vs baseline: 1.2336x; 1.0100x over previous
//
#include <hip/hip_runtime.h>
#include <cstdint>
#include <cstddef>

#define NB 8
#define NS 4096
#define NN 2048
#define NH 768
#define NK 50
#define SEG 256
#define NSEG (NS / SEG)    // 16

// ---------------------------------------------------------------------------
// K1a: sequential f32 chain per (b,h) column, NO per-row stores — only the
// accumulator at each 256-row boundary (checkpoint). Store-free inner loop
// lets the 2x64 register double-buffer keep ~63 loads in flight (vmcnt cap).
// Bit-exact np.cumsum order.
// ---------------------------------------------------------------------------
__global__ __launch_bounds__(64) void k1a_chk(const float* __restrict__ x,
                                              float* __restrict__ chk) {
  const int w = blockIdx.x;                 // 0..95 = 8 b x 12 h-slices
  const int b = w / 12;
  const int h = (w % 12) * 64 + threadIdx.x;
  const float* gx = x + (size_t)b * NS * NH + h;

  float va[64], vb[64];
#pragma unroll
  for (int j = 0; j < 64; ++j) va[j] = gx[(size_t)j * NH];

  float acc = 0.0f;
  for (int c = 0; c < 64; c += 2) {
    {   // load chunk c+1 (always exists)
      const float* s = gx + (size_t)(c + 1) * 64 * NH;
#pragma unroll
      for (int j = 0; j < 64; ++j) vb[j] = s[(size_t)j * NH];
    }
#pragma unroll
    for (int j = 0; j < 64; ++j) acc += va[j];       // chunk c
    if (c + 2 < 64) {
      const float* s = gx + (size_t)(c + 2) * 64 * NH;
#pragma unroll
      for (int j = 0; j < 64; ++j) va[j] = s[(size_t)j * NH];
    }
#pragma unroll
    for (int j = 0; j < 64; ++j) acc += vb[j];       // chunk c+1
    // after chunk c+1: row boundary 64*(c+2); checkpoint when %256==0
    if ((c & 3) == 2 && c + 2 < 64)
      chk[((size_t)b * NSEG + (size_t)(c + 2) / 4) * NH + h] = acc;
  }
}

// ---------------------------------------------------------------------------
// K1b: fill P. 1536 waves; each replays one 256-row segment from its exact
// checkpoint accumulator -> identical f32 add sequence -> bit-exact cumsum.
// ---------------------------------------------------------------------------
__global__ __launch_bounds__(256) void k1b_fill(const float* __restrict__ x,
                                                const float* __restrict__ chk,
                                                float* __restrict__ P) {
  const int gw   = blockIdx.x * 4 + (threadIdx.x >> 6);   // 0..1535
  const int lane = threadIdx.x & 63;
  const int b    = gw / (12 * NSEG);
  const int rem  = gw % (12 * NSEG);
  const int slice = rem / NSEG, seg = rem % NSEG;
  const int h = slice * 64 + lane;

  const float* gx = x + ((size_t)b * NS + (size_t)seg * SEG) * NH + h;
  float*       gp = P + ((size_t)b * (NS + 1) + (size_t)seg * SEG + 1) * NH + h;

  if (seg == 0) P[(size_t)b * (NS + 1) * NH + h] = 0.0f;  // P[b,0,h] = 0
  float acc = (seg == 0) ? 0.0f : chk[((size_t)b * NSEG + seg) * NH + h];

  float va[32], vb[32];
#pragma unroll
  for (int j = 0; j < 32; ++j) va[j] = gx[(size_t)j * NH];

  for (int c = 0; c < 8; c += 2) {
    {   // load chunk c+1
      const float* s = gx + (size_t)(c + 1) * 32 * NH;
#pragma unroll
      for (int j = 0; j < 32; ++j) vb[j] = s[(size_t)j * NH];
    }
    {   // consume chunk c
      float* op = gp + (size_t)c * 32 * NH;
#pragma unroll
      for (int j = 0; j < 32; ++j) { acc += va[j]; op[(size_t)j * NH] = acc; }
    }
    if (c + 2 < 8) {
      const float* s = gx + (size_t)(c + 2) * 32 * NH;
#pragma unroll
      for (int j = 0; j < 32; ++j) va[j] = s[(size_t)j * NH];
    }
    {   // consume chunk c+1
      float* op = gp + (size_t)(c + 1) * 32 * NH;
#pragma unroll
      for (int j = 0; j < 32; ++j) { acc += vb[j]; op[(size_t)j * NH] = acc; }
    }
  }
}

// ---------------------------------------------------------------------------
// K2: span scores. [UNCHANGED from passing version]
// ---------------------------------------------------------------------------
__global__ __launch_bounds__(256) void k2_scores(const float* __restrict__ P,
                                                 const int* __restrict__ starts,
                                                 const int* __restrict__ lens,
                                                 const float* __restrict__ anchor,
                                                 float* __restrict__ scores) {
  const int lane  = threadIdx.x & 63;
  const int gwave = blockIdx.x * 4 + (threadIdx.x >> 6);
  const int nwv   = gridDim.x * 4;

  float4 a[3][3];
#pragma unroll
  for (int c = 0; c < 3; ++c)
#pragma unroll
    for (int p = 0; p < 3; ++p)
      a[c][p] = *reinterpret_cast<const float4*>(anchor + c * NH + lane * 4 + p * 256);

  for (int sp = gwave; sp < NB * NN; sp += nwv) {
    const int b  = sp >> 11;
    const int st = starts[sp];
    const int nt = lens[sp] + 1;
    const int en = st + nt;
    const float fnt = (float)nt;
    const float* ps = P + ((size_t)b * (NS + 1) + st) * NH + lane * 4;
    const float* pe = P + ((size_t)b * (NS + 1) + en) * NH + lane * 4;
    float d0 = 0.f, d1 = 0.f, d2 = 0.f;
#pragma unroll
    for (int p = 0; p < 3; ++p) {
      float4 vs = *reinterpret_cast<const float4*>(ps + p * 256);
      float4 ve = *reinterpret_cast<const float4*>(pe + p * 256);
      float ex = (ve.x - vs.x) / fnt;
      float ey = (ve.y - vs.y) / fnt;
      float ez = (ve.z - vs.z) / fnt;
      float ew = (ve.w - vs.w) / fnt;
      d0 += ex * a[0][p].x + ey * a[0][p].y + ez * a[0][p].z + ew * a[0][p].w;
      d1 += ex * a[1][p].x + ey * a[1][p].y + ez * a[1][p].z + ew * a[1][p].w;
      d2 += ex * a[2][p].x + ey * a[2][p].y + ez * a[2][p].z + ew * a[2][p].w;
    }
#pragma unroll
    for (int o = 32; o > 0; o >>= 1) {
      d0 += __shfl_xor(d0, o);
      d1 += __shfl_xor(d1, o);
      d2 += __shfl_xor(d2, o);
    }
    if (lane == 0) scores[sp] = fmaxf(d0, fmaxf(d1, d2));
  }
}

// ---------------------------------------------------------------------------
// K3: top-50 per batch. [UNCHANGED]
// ---------------------------------------------------------------------------
__global__ __launch_bounds__(256) void k3_topk(const float* __restrict__ scores,
                                               int* __restrict__ topidx) {
  const int b   = blockIdx.x;
  const int tid = threadIdx.x;
  __shared__ unsigned long long key[NN];
  __shared__ unsigned long long red[256];
  for (int i = tid; i < NN; i += 256) {
    unsigned u   = __float_as_uint(scores[b * NN + i]);
    unsigned ord = (u & 0x80000000u) ? ~u : (u | 0x80000000u);
    key[i] = ((unsigned long long)ord << 32) | (unsigned)(NN - 1 - i);
  }
  __syncthreads();
  for (int k = 0; k < NK; ++k) {
    unsigned long long m = 0;
    for (int i = tid; i < NN; i += 256) m = (key[i] > m) ? key[i] : m;
    red[tid] = m;
    __syncthreads();
    for (int s2 = 128; s2 > 0; s2 >>= 1) {
      if (tid < s2) { if (red[tid + s2] > red[tid]) red[tid] = red[tid + s2]; }
      __syncthreads();
    }
    if (tid == 0) {
      int n = (NN - 1) - (int)(red[0] & 0xFFFFFFFFull);
      topidx[b * NK + k] = n;
      key[n] = 0;
    }
    __syncthreads();
  }
}

// ---------------------------------------------------------------------------
// K4a: projections for 400 selected spans. [UNCHANGED]
// ---------------------------------------------------------------------------
__global__ __launch_bounds__(256) void k4a_proj(const float* __restrict__ P,
                                                const int* __restrict__ starts,
                                                const int* __restrict__ lens,
                                                const int* __restrict__ topidx,
                                                const float* __restrict__ rel,
                                                const float* __restrict__ nota,
                                                float* __restrict__ proj) {
  const int gw   = blockIdx.x * 4 + (threadIdx.x >> 6);   // 0..399
  const int lane = threadIdx.x & 63;
  const int b = gw / NK, k = gw % NK;
  const int n  = topidx[b * NK + k];
  const int st = starts[b * NN + n];
  const int nt = lens[b * NN + n] + 1;
  const int en = st + nt;
  const float fnt = (float)nt;
  const float* ps = P + ((size_t)b * (NS + 1) + st) * NH + lane * 4;
  const float* pe = P + ((size_t)b * (NS + 1) + en) * NH + lane * 4;
  float4 e[3];
#pragma unroll
  for (int p = 0; p < 3; ++p) {
    float4 vs = *reinterpret_cast<const float4*>(ps + p * 256);
    float4 ve = *reinterpret_cast<const float4*>(pe + p * 256);
    e[p].x = (ve.x - vs.x) / fnt;
    e[p].y = (ve.y - vs.y) / fnt;
    e[p].z = (ve.z - vs.z) / fnt;
    e[p].w = (ve.w - vs.w) / fnt;
  }
  for (int w = 0; w < 48; ++w) {
    const float* wr;
    if (w < 4)       wr = rel  + (size_t)w * (2 * NH);
    else if (w < 8)  wr = rel  + (size_t)(w - 4) * (2 * NH) + NH;
    else if (w < 28) wr = nota + (size_t)(w - 8) * (2 * NH);
    else             wr = nota + (size_t)(w - 28) * (2 * NH) + NH;
    wr += lane * 4;
    float d = 0.f;
#pragma unroll
    for (int p = 0; p < 3; ++p) {
      float4 wv = *reinterpret_cast<const float4*>(wr + p * 256);
      d += e[p].x * wv.x + e[p].y * wv.y + e[p].z * wv.z + e[p].w * wv.w;
    }
#pragma unroll
    for (int o = 32; o > 0; o >>= 1) d += __shfl_xor(d, o);
    if (lane == 0) proj[((size_t)b * NK + k) * 48 + w] = d;
  }
}

// ---------------------------------------------------------------------------
// K4b: epilogue. [UNCHANGED]
// ---------------------------------------------------------------------------
__global__ __launch_bounds__(256) void k4b_out(const float* __restrict__ proj,
                                               float* __restrict__ out) {
  int idx = blockIdx.x * 256 + threadIdx.x;
  if (idx >= NB * NK * NK) return;
  int b  = idx / (NK * NK);
  int rr = idx % (NK * NK);
  int k1 = rr / NK, k2 = rr % NK;
  const float* p1 = proj + ((size_t)b * NK + k1) * 48;
  const float* p2 = proj + ((size_t)b * NK + k2) * 48;
  float mx = p1[8] + p2[28];
#pragma unroll
  for (int m = 1; m < 20; ++m) mx = fmaxf(mx, p1[8 + m] + p2[28 + m]);
  float* o = out + (size_t)idx * 5;
  o[0] = mx;
#pragma unroll
  for (int r = 0; r < 4; ++r) o[1 + r] = p1[r] + p2[4 + r];
}

// ---------------------------------------------------------------------------
extern "C" void kernel_launch(void* const* d_in, const int* in_sizes, int n_in,
                              void* d_out, int out_size, void* d_ws, size_t ws_size,
                              hipStream_t stream) {
  const float* x      = (const float*)d_in[0];
  const int*   starts = (const int*)d_in[1];
  const int*   lens   = (const int*)d_in[2];
  const float* anchor = (const float*)d_in[3];
  const float* rel    = (const float*)d_in[4];
  const float* nota   = (const float*)d_in[5];
  float* out = (float*)d_out;

  char*  ws     = (char*)d_ws;
  size_t pbytes = (size_t)NB * (NS + 1) * NH * sizeof(float);  // ~100.7 MB
  float* P      = (float*)ws;
  float* scores = (float*)(ws + pbytes);
  int*   topidx = (int*)(ws + pbytes + (size_t)NB * NN * sizeof(float));
  float* proj   = (float*)(ws + pbytes + (size_t)NB * NN * sizeof(float) + 4096);
  float* chk    = (float*)(ws + pbytes + (size_t)NB * NN * sizeof(float) + 4096
                           + (size_t)NB * NK * 48 * sizeof(float));

  hipLaunchKernelGGL(k1a_chk, dim3(NB * (NH / 64)), dim3(64), 0, stream, x, chk);
  hipLaunchKernelGGL(k1b_fill, dim3(NB * (NH / 64) * NSEG / 4), dim3(256), 0, stream,
                     x, chk, P);
  hipLaunchKernelGGL(k2_scores, dim3(1024), dim3(256), 0, stream,
                     P, starts, lens, anchor, scores);
  hipLaunchKernelGGL(k3_topk, dim3(NB), dim3(256), 0, stream, scores, topidx);
  hipLaunchKernelGGL(k4a_proj, dim3(NB * NK / 4), dim3(256), 0, stream,
                     P, starts, lens, topidx, rel, nota, proj);
  hipLaunchKernelGGL(k4b_out, dim3((NB * NK * NK + 255) / 256), dim3(256), 0, stream,
                     proj, out);
}